// Round 1
// baseline (2051.280 us; speedup 1.0000x reference)
//
#include <hip/hip_runtime.h>

#define NB   2
#define SEQ  2048
#define EMB  1024
#define NH   16
#define HD   64
#define SCALE 0.03125f   // 1/sqrt(1024)

// ---------------------------------------------------------------------------
// Kernel 1: per-head QKV projection.  grid (SEQ/64, NH, 3*NB), block 256.
// Treats each (tensor t, n, h) as a GEMM: X[l,d] (64x64 tile) @ W[e,d]^T.
// ---------------------------------------------------------------------------
__global__ __launch_bounds__(256) void qkv_proj_kernel(
    const float* __restrict__ Qin, const float* __restrict__ Kin,
    const float* __restrict__ Vin,
    const float* __restrict__ Wq, const float* __restrict__ Wk,
    const float* __restrict__ Wv, const float* __restrict__ bq,
    float* __restrict__ Qp, float* __restrict__ Kp, float* __restrict__ Vp)
{
    const int lt = blockIdx.x;          // l tile (64 rows)
    const int h  = blockIdx.y;
    const int tz = blockIdx.z;          // t*NB + n
    const int t  = tz >> 1;             // 0=q, 1=k, 2=v
    const int n  = tz & 1;

    const float* X; const float* W; float* Out;
    if (t == 0)      { X = Qin; W = Wq; Out = Qp; }
    else if (t == 1) { X = Kin; W = Wk; Out = Kp; }
    else             { X = Vin; W = Wv; Out = Vp; }

    __shared__ float sX[64][68];   // [l][d], pad 68 (16B aligned, bank-safe)
    __shared__ float sW[64][68];   // [e][d]

    const int tid = threadIdx.x;
    #pragma unroll
    for (int it = 0; it < 4; ++it) {
        int flat = tid + it * 256;           // float4 index 0..1023
        int r = flat >> 4, c4 = flat & 15;
        *(float4*)&sX[r][c4 * 4] =
            *(const float4*)(X + ((size_t)(n * SEQ + lt * 64 + r)) * EMB + h * HD + c4 * 4);
        *(float4*)&sW[r][c4 * 4] = *(const float4*)(W + r * HD + c4 * 4);
    }
    __syncthreads();

    const int lg = tid >> 4;   // q-row group (4 rows)
    const int eg = tid & 15;   // e-col group (4 cols)
    float acc[4][4] = {};

    #pragma unroll
    for (int dd = 0; dd < 16; ++dd) {
        float4 xr[4], wr[4];
        #pragma unroll
        for (int a = 0; a < 4; ++a) xr[a] = *(const float4*)&sX[lg * 4 + a][dd * 4];
        #pragma unroll
        for (int b = 0; b < 4; ++b) wr[b] = *(const float4*)&sW[eg * 4 + b][dd * 4];
        #pragma unroll
        for (int a = 0; a < 4; ++a)
            #pragma unroll
            for (int b = 0; b < 4; ++b)
                acc[a][b] += xr[a].x * wr[b].x + xr[a].y * wr[b].y +
                             xr[a].z * wr[b].z + xr[a].w * wr[b].w;
    }

    if (t == 0) {
        #pragma unroll
        for (int b = 0; b < 4; ++b) {
            float bias = bq[eg * 4 + b];
            #pragma unroll
            for (int a = 0; a < 4; ++a) acc[a][b] += bias;
        }
    }

    // store to [n][h][l][d]
    #pragma unroll
    for (int a = 0; a < 4; ++a) {
        float4 o = make_float4(acc[a][0], acc[a][1], acc[a][2], acc[a][3]);
        *(float4*)(Out + ((size_t)((n * NH + h) * SEQ + lt * 64 + lg * 4 + a)) * HD + eg * 4) = o;
    }
}

// ---------------------------------------------------------------------------
// Kernel 2: flash attention (fp32).  grid (SEQ/64, NB*NH), block 256.
// Q tile 64x64 resident; stream K/V tiles of 64 rows; online softmax.
// ---------------------------------------------------------------------------
__global__ __launch_bounds__(256) void flash_kernel(
    const float* __restrict__ Qp, const float* __restrict__ Kp,
    const float* __restrict__ Vp, const int* __restrict__ mask,
    float* __restrict__ A /* [n][l][EMB] */)
{
    const int qt = blockIdx.x;
    const int nh = blockIdx.y;
    const int n  = nh / NH;
    const int h  = nh % NH;
    const float* Qb = Qp + (size_t)nh * SEQ * HD + (size_t)qt * 64 * HD;
    const float* Kb = Kp + (size_t)nh * SEQ * HD;
    const float* Vb = Vp + (size_t)nh * SEQ * HD;
    const int*   mb = mask + n * SEQ;

    __shared__ float sQ[64][68], sK[64][68], sV[64][68], sP[64][68];

    const int tid = threadIdx.x;
    const int qg  = tid >> 4;    // 4 q rows
    const int kg  = tid & 15;    // 4 k cols in S phase; 4 d cols in PV phase

    #pragma unroll
    for (int it = 0; it < 4; ++it) {
        int flat = tid + it * 256; int r = flat >> 4, c4 = flat & 15;
        *(float4*)&sQ[r][c4 * 4] = *(const float4*)(Qb + r * HD + c4 * 4);
    }

    float Oacc[4][4] = {};
    float m_i[4], l_i[4];
    #pragma unroll
    for (int a = 0; a < 4; ++a) { m_i[a] = -__builtin_inff(); l_i[a] = 0.f; }

    for (int kt = 0; kt < SEQ / 64; ++kt) {
        __syncthreads();   // prev iteration's PV readers done before K/V rewrite
        #pragma unroll
        for (int it = 0; it < 4; ++it) {
            int flat = tid + it * 256; int r = flat >> 4, c4 = flat & 15;
            *(float4*)&sK[r][c4 * 4] = *(const float4*)(Kb + (kt * 64 + r) * HD + c4 * 4);
            *(float4*)&sV[r][c4 * 4] = *(const float4*)(Vb + (kt * 64 + r) * HD + c4 * 4);
        }
        __syncthreads();

        // ---- S = Q K^T (4x4 per thread) ----
        float s[4][4] = {};
        #pragma unroll
        for (int dd = 0; dd < 16; ++dd) {
            float4 qr[4], kr[4];
            #pragma unroll
            for (int a = 0; a < 4; ++a) qr[a] = *(const float4*)&sQ[qg * 4 + a][dd * 4];
            #pragma unroll
            for (int b = 0; b < 4; ++b) kr[b] = *(const float4*)&sK[kg * 4 + b][dd * 4];
            #pragma unroll
            for (int a = 0; a < 4; ++a)
                #pragma unroll
                for (int b = 0; b < 4; ++b)
                    s[a][b] += qr[a].x * kr[b].x + qr[a].y * kr[b].y +
                               qr[a].z * kr[b].z + qr[a].w * kr[b].w;
        }

        // ---- mask + scale (reference: mask applied pre-scale at -1e20) ----
        int mv[4];
        #pragma unroll
        for (int b = 0; b < 4; ++b) mv[b] = mb[kt * 64 + kg * 4 + b];
        #pragma unroll
        for (int a = 0; a < 4; ++a)
            #pragma unroll
            for (int b = 0; b < 4; ++b)
                s[a][b] = mv[b] ? s[a][b] * SCALE : -3.125e18f;

        // ---- online softmax per q row (16 lanes per row share state) ----
        #pragma unroll
        for (int a = 0; a < 4; ++a) {
            float rm = fmaxf(fmaxf(s[a][0], s[a][1]), fmaxf(s[a][2], s[a][3]));
            #pragma unroll
            for (int off = 1; off < 16; off <<= 1)
                rm = fmaxf(rm, __shfl_xor(rm, off));
            float mn    = fmaxf(m_i[a], rm);
            float alpha = __expf(m_i[a] - mn);
            float p0 = __expf(s[a][0] - mn);
            float p1 = __expf(s[a][1] - mn);
            float p2 = __expf(s[a][2] - mn);
            float p3 = __expf(s[a][3] - mn);
            float rs = p0 + p1 + p2 + p3;
            #pragma unroll
            for (int off = 1; off < 16; off <<= 1)
                rs += __shfl_xor(rs, off);
            l_i[a] = l_i[a] * alpha + rs;
            m_i[a] = mn;
            #pragma unroll
            for (int c = 0; c < 4; ++c) Oacc[a][c] *= alpha;
            *(float4*)&sP[qg * 4 + a][kg * 4] = make_float4(p0, p1, p2, p3);
        }
        __syncthreads();

        // ---- O += P V  (kg now indexes 4 d cols) ----
        for (int k4 = 0; k4 < 16; ++k4) {
            float pr[4][4];
            #pragma unroll
            for (int a = 0; a < 4; ++a)
                *(float4*)&pr[a][0] = *(const float4*)&sP[qg * 4 + a][k4 * 4];
            #pragma unroll
            for (int j = 0; j < 4; ++j) {
                float4 vv = *(const float4*)&sV[k4 * 4 + j][kg * 4];
                #pragma unroll
                for (int a = 0; a < 4; ++a) {
                    Oacc[a][0] += pr[a][j] * vv.x;
                    Oacc[a][1] += pr[a][j] * vv.y;
                    Oacc[a][2] += pr[a][j] * vv.z;
                    Oacc[a][3] += pr[a][j] * vv.w;
                }
            }
        }
    }

    // ---- epilogue: normalize, store to [n][l][h*64+d] ----
    #pragma unroll
    for (int a = 0; a < 4; ++a) {
        float inv = 1.0f / l_i[a];
        float4 o = make_float4(Oacc[a][0] * inv, Oacc[a][1] * inv,
                               Oacc[a][2] * inv, Oacc[a][3] * inv);
        *(float4*)(A + ((size_t)(n * SEQ + qt * 64 + qg * 4 + a)) * EMB + h * HD + kg * 4) = o;
    }
}

// ---------------------------------------------------------------------------
// Kernel 3: output projection  Out = A @ Wo^T + bo.
// grid (EMB/64, NB*SEQ/64), block 256.
// ---------------------------------------------------------------------------
__global__ __launch_bounds__(256) void outproj_kernel(
    const float* __restrict__ A, const float* __restrict__ Wo,
    const float* __restrict__ bo, float* __restrict__ Out)
{
    const int ct = blockIdx.x;
    const int rt = blockIdx.y;
    __shared__ float sA[64][68], sW[64][68];
    const int tid = threadIdx.x;
    const int rg = tid >> 4, cg = tid & 15;
    float acc[4][4] = {};

    for (int kc = 0; kc < EMB / 64; ++kc) {
        __syncthreads();
        #pragma unroll
        for (int it = 0; it < 4; ++it) {
            int flat = tid + it * 256; int r = flat >> 4, c4 = flat & 15;
            *(float4*)&sA[r][c4 * 4] =
                *(const float4*)(A + ((size_t)(rt * 64 + r)) * EMB + kc * 64 + c4 * 4);
            *(float4*)&sW[r][c4 * 4] =
                *(const float4*)(Wo + ((size_t)(ct * 64 + r)) * EMB + kc * 64 + c4 * 4);
        }
        __syncthreads();
        #pragma unroll
        for (int dd = 0; dd < 16; ++dd) {
            float4 ar[4], wr[4];
            #pragma unroll
            for (int a = 0; a < 4; ++a) ar[a] = *(const float4*)&sA[rg * 4 + a][dd * 4];
            #pragma unroll
            for (int b = 0; b < 4; ++b) wr[b] = *(const float4*)&sW[cg * 4 + b][dd * 4];
            #pragma unroll
            for (int a = 0; a < 4; ++a)
                #pragma unroll
                for (int b = 0; b < 4; ++b)
                    acc[a][b] += ar[a].x * wr[b].x + ar[a].y * wr[b].y +
                                 ar[a].z * wr[b].z + ar[a].w * wr[b].w;
        }
    }

    #pragma unroll
    for (int a = 0; a < 4; ++a) {
        int row = rt * 64 + rg * 4 + a;
        float4 o = make_float4(acc[a][0] + bo[ct * 64 + cg * 4 + 0],
                               acc[a][1] + bo[ct * 64 + cg * 4 + 1],
                               acc[a][2] + bo[ct * 64 + cg * 4 + 2],
                               acc[a][3] + bo[ct * 64 + cg * 4 + 3]);
        *(float4*)(Out + (size_t)row * EMB + ct * 64 + cg * 4) = o;
    }
}

// ---------------------------------------------------------------------------
extern "C" void kernel_launch(void* const* d_in, const int* in_sizes, int n_in,
                              void* d_out, int out_size, void* d_ws, size_t ws_size,
                              hipStream_t stream) {
    const float* values = (const float*)d_in[0];
    const float* key_   = (const float*)d_in[1];
    const float* query  = (const float*)d_in[2];
    const int*   mask   = (const int*)d_in[3];
    const float* Wv     = (const float*)d_in[4];
    const float* Wk     = (const float*)d_in[5];
    const float* Wq     = (const float*)d_in[6];
    const float* bq     = (const float*)d_in[7];
    const float* Wo     = (const float*)d_in[8];
    const float* bo     = (const float*)d_in[9];
    float* out = (float*)d_out;

    float* ws = (float*)d_ws;
    const size_t NHLD = (size_t)NB * NH * SEQ * HD;   // 4,194,304 floats
    float* Qp    = ws;
    float* Kp    = ws + NHLD;
    float* Vp    = ws + 2 * NHLD;
    float* Aattn = ws + 3 * NHLD;                      // [n][l][EMB]

    qkv_proj_kernel<<<dim3(SEQ / 64, NH, 3 * NB), 256, 0, stream>>>(
        query, key_, values, Wq, Wk, Wv, bq, Qp, Kp, Vp);
    flash_kernel<<<dim3(SEQ / 64, NB * NH), 256, 0, stream>>>(
        Qp, Kp, Vp, mask, Aattn);
    outproj_kernel<<<dim3(EMB / 64, NB * SEQ / 64), 256, 0, stream>>>(
        Aattn, Wo, bo, out);
}

// Round 2
// 276.070 us; speedup vs baseline: 7.4303x; 7.4303x over previous
//
#include <hip/hip_runtime.h>

#define NB   2
#define SEQ  2048
#define EMB  1024
#define NH   16
#define HD   64
#define SCALE 0.03125f            // 1/sqrt(1024)
#define MASKED_VAL -3.125e18f     // -1e20 * SCALE (mask applied pre-scale)

typedef __attribute__((ext_vector_type(8))) short short8;   // 8 x bf16
typedef __attribute__((ext_vector_type(4))) float f32x4;    // MFMA C/D

#define MFMA(a, b, c) __builtin_amdgcn_mfma_f32_16x16x32_bf16(a, b, c, 0, 0, 0)

__device__ __forceinline__ unsigned short f2bf(float x) {
    union { float f; unsigned u; } v; v.f = x;
    unsigned r = v.u + 0x7fffu + ((v.u >> 16) & 1u);   // RNE
    return (unsigned short)(r >> 16);
}
__device__ __forceinline__ unsigned pack2(float a, float b) {
    return (unsigned)f2bf(a) | ((unsigned)f2bf(b) << 16);
}

// ---------------------------------------------------------------------------
// Kernel 1: per-head QKV projection (bf16 MFMA).
// grid (SEQ/64, NH, 3*NB), block 256 (4 waves, 16 l-rows each).
// Q,K out: [n][h][l][d] bf16.  V out TRANSPOSED: [n][h][d][l] bf16.
// ---------------------------------------------------------------------------
__global__ __launch_bounds__(256) void qkv_kernel(
    const float* __restrict__ Qin, const float* __restrict__ Kin,
    const float* __restrict__ Vin,
    const float* __restrict__ Wq, const float* __restrict__ Wk,
    const float* __restrict__ Wv, const float* __restrict__ bq,
    unsigned short* __restrict__ Qp, unsigned short* __restrict__ Kp,
    unsigned short* __restrict__ Vtp)
{
    const int lt = blockIdx.x;
    const int h  = blockIdx.y;
    const int tz = blockIdx.z;
    const int t  = tz >> 1;             // 0=q, 1=k, 2=v
    const int n  = tz & 1;

    const float* X; const float* W;
    if (t == 0)      { X = Qin; W = Wq; }
    else if (t == 1) { X = Kin; W = Wk; }
    else             { X = Vin; W = Wv; }

    __shared__ __align__(16) unsigned short sX[64][72];  // [l][d] bf16, pad 72
    __shared__ __align__(16) unsigned short sW[64][72];  // [e][d] bf16
    __shared__ __align__(16) unsigned short sT[64][72];  // V transpose buffer

    const int tid  = threadIdx.x;
    const int wave = tid >> 6, lane = tid & 63;
    const int ln   = lane & 15, quad = lane >> 4;

    // stage X (fp32 -> bf16) and W
    #pragma unroll
    for (int i = 0; i < 4; ++i) {
        int flat = tid + i * 256;              // 0..1023 float4-slots
        int r = flat >> 4, c4 = flat & 15;
        float4 xv = *(const float4*)(X + ((size_t)(n * SEQ + lt * 64 + r)) * EMB + h * HD + c4 * 4);
        uint2 xp; xp.x = pack2(xv.x, xv.y); xp.y = pack2(xv.z, xv.w);
        *(uint2*)&sX[r][c4 * 4] = xp;
        float4 wv = *(const float4*)(W + r * HD + c4 * 4);
        uint2 wp; wp.x = pack2(wv.x, wv.y); wp.y = pack2(wv.z, wv.w);
        *(uint2*)&sW[r][c4 * 4] = wp;
    }
    __syncthreads();

    // A-fragments (this wave's 16 l-rows), reused across nt
    short8 af0 = *(const short8*)&sX[wave * 16 + ln][quad * 8];
    short8 af1 = *(const short8*)&sX[wave * 16 + ln][32 + quad * 8];

    f32x4 acc[4];
    #pragma unroll
    for (int nt = 0; nt < 4; ++nt) {
        short8 bf0 = *(const short8*)&sW[nt * 16 + ln][quad * 8];
        short8 bf1 = *(const short8*)&sW[nt * 16 + ln][32 + quad * 8];
        f32x4 a = {0.f, 0.f, 0.f, 0.f};
        a = MFMA(af0, bf0, a);
        a = MFMA(af1, bf1, a);
        acc[nt] = a;
    }

    if (t == 0) {
        #pragma unroll
        for (int nt = 0; nt < 4; ++nt) {
            float bb = bq[nt * 16 + ln];
            #pragma unroll
            for (int a = 0; a < 4; ++a) acc[nt][a] += bb;
        }
    }

    if (t < 2) {
        unsigned short* Out = (t == 0) ? Qp : Kp;
        // row l = lt*64 + wave*16 + quad*4 + a ; col d = nt*16 + ln
        #pragma unroll
        for (int a = 0; a < 4; ++a) {
            size_t row = (size_t)((n * NH + h) * SEQ + lt * 64 + wave * 16 + quad * 4 + a);
            #pragma unroll
            for (int nt = 0; nt < 4; ++nt)
                Out[row * HD + nt * 16 + ln] = f2bf(acc[nt][a]);
        }
    } else {
        // transpose through LDS: sT[d][l]
        #pragma unroll
        for (int nt = 0; nt < 4; ++nt)
            #pragma unroll
            for (int a = 0; a < 4; ++a)
                sT[nt * 16 + ln][wave * 16 + quad * 4 + a] = f2bf(acc[nt][a]);
        __syncthreads();
        #pragma unroll
        for (int i = 0; i < 2; ++i) {
            int flat = tid + i * 256;          // 0..511 16B-slots
            int r = flat >> 3, c8 = flat & 7;
            *(float4*)(Vtp + ((size_t)((n * NH + h) * HD + r)) * SEQ + lt * 64 + c8 * 8) =
                *(const float4*)&sT[r][c8 * 8];
        }
    }
}

// ---------------------------------------------------------------------------
// Kernel 2: flash attention, bf16 MFMA, fp32 online softmax.
// grid (SEQ/64, NB*NH), block 256 (4 waves, 16 q-rows each).
// ---------------------------------------------------------------------------
__global__ __launch_bounds__(256) void flash_kernel(
    const unsigned short* __restrict__ Qp, const unsigned short* __restrict__ Kp,
    const unsigned short* __restrict__ Vtp, const int* __restrict__ mask,
    unsigned short* __restrict__ A /* [n][l][EMB] bf16 */)
{
    const int qt = blockIdx.x;
    const int nh = blockIdx.y;
    const int n  = nh >> 4, h = nh & 15;

    const int tid  = threadIdx.x;
    const int wave = tid >> 6, lane = tid & 63;
    const int ln   = lane & 15, quad = lane >> 4;

    __shared__ __align__(16) unsigned short sK [64][72];  // [key][d]
    __shared__ __align__(16) unsigned short sVt[64][72];  // [d][key]
    __shared__ __align__(16) unsigned short sP [64][72];  // per-wave 16-row slices
    __shared__ int sMask[SEQ];

    for (int i = tid; i < SEQ; i += 256) sMask[i] = mask[n * SEQ + i];

    // Q A-fragments straight from global (row l, 16B aligned)
    const unsigned short* Qb = Qp + ((size_t)nh * SEQ + qt * 64 + wave * 16 + ln) * HD;
    short8 qf0 = *(const short8*)(Qb + quad * 8);
    short8 qf1 = *(const short8*)(Qb + 32 + quad * 8);

    const unsigned short* Kb = Kp  + (size_t)nh * SEQ * HD;
    const unsigned short* Vb = Vtp + (size_t)nh * HD * SEQ;

    f32x4 o[4];
    #pragma unroll
    for (int dt = 0; dt < 4; ++dt) o[dt] = (f32x4){0.f, 0.f, 0.f, 0.f};
    float m_i[4], l_i[4];
    #pragma unroll
    for (int a = 0; a < 4; ++a) { m_i[a] = -1e30f; l_i[a] = 0.f; }

    for (int kt = 0; kt < SEQ / 64; ++kt) {
        __syncthreads();   // previous iteration's readers done
        #pragma unroll
        for (int i = 0; i < 2; ++i) {
            int flat = tid + i * 256; int r = flat >> 3, c8 = flat & 7;
            *(float4*)&sK [r][c8 * 8] = *(const float4*)(Kb + ((size_t)(kt * 64 + r)) * HD + c8 * 8);
            *(float4*)&sVt[r][c8 * 8] = *(const float4*)(Vb + (size_t)r * SEQ + kt * 64 + c8 * 8);
        }
        __syncthreads();

        // ---- S = Q K^T : 4 n-tiles x 2 k-steps ----
        f32x4 s[4];
        #pragma unroll
        for (int nt = 0; nt < 4; ++nt) {
            short8 b0 = *(const short8*)&sK[nt * 16 + ln][quad * 8];
            short8 b1 = *(const short8*)&sK[nt * 16 + ln][32 + quad * 8];
            f32x4 a = {0.f, 0.f, 0.f, 0.f};
            a = MFMA(qf0, b0, a);
            a = MFMA(qf1, b1, a);
            s[nt] = a;
        }

        int mv[4];
        #pragma unroll
        for (int nt = 0; nt < 4; ++nt) mv[nt] = sMask[kt * 64 + nt * 16 + ln];

        // ---- fp32 online softmax; row = quad*4 + a, col = nt*16 + ln ----
        #pragma unroll
        for (int a = 0; a < 4; ++a) {
            float sa[4];
            #pragma unroll
            for (int nt = 0; nt < 4; ++nt)
                sa[nt] = mv[nt] ? s[nt][a] * SCALE : MASKED_VAL;
            float rm = fmaxf(fmaxf(sa[0], sa[1]), fmaxf(sa[2], sa[3]));
            #pragma unroll
            for (int off = 1; off < 16; off <<= 1) rm = fmaxf(rm, __shfl_xor(rm, off));
            float mn    = fmaxf(m_i[a], rm);
            float alpha = __expf(m_i[a] - mn);
            float rs = 0.f;
            float pv[4];
            #pragma unroll
            for (int nt = 0; nt < 4; ++nt) { pv[nt] = __expf(sa[nt] - mn); rs += pv[nt]; }
            #pragma unroll
            for (int off = 1; off < 16; off <<= 1) rs += __shfl_xor(rs, off);
            l_i[a] = l_i[a] * alpha + rs;
            m_i[a] = mn;
            #pragma unroll
            for (int dt = 0; dt < 4; ++dt) o[dt][a] *= alpha;
            #pragma unroll
            for (int nt = 0; nt < 4; ++nt)
                sP[wave * 16 + quad * 4 + a][nt * 16 + ln] = f2bf(pv[nt]);
        }

        // per-wave LDS region: only need lgkm drain, no barrier
        asm volatile("s_waitcnt lgkmcnt(0)" ::: "memory");

        // ---- O += P V ----
        short8 pf0 = *(const short8*)&sP[wave * 16 + ln][quad * 8];
        short8 pf1 = *(const short8*)&sP[wave * 16 + ln][32 + quad * 8];
        #pragma unroll
        for (int dt = 0; dt < 4; ++dt) {
            short8 v0 = *(const short8*)&sVt[dt * 16 + ln][quad * 8];
            short8 v1 = *(const short8*)&sVt[dt * 16 + ln][32 + quad * 8];
            o[dt] = MFMA(pf0, v0, o[dt]);
            o[dt] = MFMA(pf1, v1, o[dt]);
        }
    }

    // ---- epilogue: normalize, store bf16 [n][l][h*64+d] ----
    #pragma unroll
    for (int a = 0; a < 4; ++a) {
        float inv = 1.0f / l_i[a];
        size_t row = (size_t)(n * SEQ + qt * 64 + wave * 16 + quad * 4 + a);
        #pragma unroll
        for (int dt = 0; dt < 4; ++dt)
            A[row * EMB + h * HD + dt * 16 + ln] = f2bf(o[dt][a] * inv);
    }
}

// ---------------------------------------------------------------------------
// Kernel 3: out = A @ Wo^T + bo (bf16 MFMA, fp32 out).
// grid (EMB/64, NB*SEQ/64), block 256 (4 waves, 16 rows each).
// ---------------------------------------------------------------------------
__global__ __launch_bounds__(256) void outproj_kernel(
    const unsigned short* __restrict__ A, const float* __restrict__ Wo,
    const float* __restrict__ bo, float* __restrict__ Out)
{
    const int ct = blockIdx.x;   // 64-col tile of EMB
    const int rt = blockIdx.y;   // 64-row tile of NB*SEQ

    const int tid  = threadIdx.x;
    const int wave = tid >> 6, lane = tid & 63;
    const int ln   = lane & 15, quad = lane >> 4;

    __shared__ __align__(16) unsigned short sA[64][72];  // [row][k]
    __shared__ __align__(16) unsigned short sW[64][72];  // [col][k]

    f32x4 acc[4];
    #pragma unroll
    for (int nt = 0; nt < 4; ++nt) acc[nt] = (f32x4){0.f, 0.f, 0.f, 0.f};

    for (int kc = 0; kc < EMB / 64; ++kc) {
        __syncthreads();
        #pragma unroll
        for (int i = 0; i < 2; ++i) {
            int flat = tid + i * 256; int r = flat >> 3, c8 = flat & 7;
            *(float4*)&sA[r][c8 * 8] =
                *(const float4*)(A + (size_t)(rt * 64 + r) * EMB + kc * 64 + c8 * 8);
        }
        #pragma unroll
        for (int i = 0; i < 4; ++i) {
            int flat = tid + i * 256; int r = flat >> 4, c4 = flat & 15;
            float4 wv = *(const float4*)(Wo + (size_t)(ct * 64 + r) * EMB + kc * 64 + c4 * 4);
            uint2 wp; wp.x = pack2(wv.x, wv.y); wp.y = pack2(wv.z, wv.w);
            *(uint2*)&sW[r][c4 * 4] = wp;
        }
        __syncthreads();

        short8 af0 = *(const short8*)&sA[wave * 16 + ln][quad * 8];
        short8 af1 = *(const short8*)&sA[wave * 16 + ln][32 + quad * 8];
        #pragma unroll
        for (int nt = 0; nt < 4; ++nt) {
            short8 bf0 = *(const short8*)&sW[nt * 16 + ln][quad * 8];
            short8 bf1 = *(const short8*)&sW[nt * 16 + ln][32 + quad * 8];
            acc[nt] = MFMA(af0, bf0, acc[nt]);
            acc[nt] = MFMA(af1, bf1, acc[nt]);
        }
    }

    #pragma unroll
    for (int nt = 0; nt < 4; ++nt) {
        float bb = bo[ct * 64 + nt * 16 + ln];
        #pragma unroll
        for (int a = 0; a < 4; ++a) {
            size_t row = (size_t)(rt * 64 + wave * 16 + quad * 4 + a);
            Out[row * EMB + ct * 64 + nt * 16 + ln] = acc[nt][a] + bb;
        }
    }
}

// ---------------------------------------------------------------------------
extern "C" void kernel_launch(void* const* d_in, const int* in_sizes, int n_in,
                              void* d_out, int out_size, void* d_ws, size_t ws_size,
                              hipStream_t stream) {
    const float* values = (const float*)d_in[0];
    const float* key_   = (const float*)d_in[1];
    const float* query  = (const float*)d_in[2];
    const int*   mask   = (const int*)d_in[3];
    const float* Wv     = (const float*)d_in[4];
    const float* Wk     = (const float*)d_in[5];
    const float* Wq     = (const float*)d_in[6];
    const float* bq     = (const float*)d_in[7];
    const float* Wo     = (const float*)d_in[8];
    const float* bo     = (const float*)d_in[9];
    float* out = (float*)d_out;

    unsigned short* ws = (unsigned short*)d_ws;
    const size_t NHLD = (size_t)NB * NH * SEQ * HD;   // 4,194,304 elements
    unsigned short* Qp    = ws;
    unsigned short* Kp    = ws + NHLD;
    unsigned short* Vtp   = ws + 2 * NHLD;
    unsigned short* Aattn = ws + 3 * NHLD;            // [n][l][EMB] bf16

    qkv_kernel<<<dim3(SEQ / 64, NH, 3 * NB), 256, 0, stream>>>(
        query, key_, values, Wq, Wk, Wv, bq, Qp, Kp, Vtp);
    flash_kernel<<<dim3(SEQ / 64, NB * NH), 256, 0, stream>>>(
        Qp, Kp, Vtp, mask, Aattn);
    outproj_kernel<<<dim3(EMB / 64, NB * SEQ / 64), 256, 0, stream>>>(
        Aattn, Wo, bo, out);
}

// Round 3
// 217.208 us; speedup vs baseline: 9.4439x; 1.2710x over previous
//
#include <hip/hip_runtime.h>
#include <hip/hip_bf16.h>
#include <string.h>

#define NB   2
#define SEQ  2048
#define EMB  1024
#define NH   16
#define HD   64
#define SCALE 0.03125f            // 1/sqrt(1024), folded into Q (exact pow2)
#define MADD  -3.125e18f          // -1e20 * SCALE additive mask value

typedef __attribute__((ext_vector_type(8))) short short8;   // 8 x bf16
typedef __attribute__((ext_vector_type(4))) float f32x4;    // MFMA C/D

#define MFMA(a, b, c) __builtin_amdgcn_mfma_f32_16x16x32_bf16(a, b, c, 0, 0, 0)

__device__ __forceinline__ unsigned short f2bf(float x) {
    union { float f; unsigned u; } v; v.f = x;
    unsigned r = v.u + 0x7fffu + ((v.u >> 16) & 1u);   // RNE
    return (unsigned short)(r >> 16);
}
__device__ __forceinline__ unsigned packbf2(float a, float b) {
    __hip_bfloat162 h = __float22bfloat162_rn(make_float2(a, b));  // hw v_cvt_pk
    unsigned u; memcpy(&u, &h, 4);
    return u;
}

// ---------------------------------------------------------------------------
// Kernel 0: Wo fp32 -> bf16, once.  grid 1024 x 256.
// ---------------------------------------------------------------------------
__global__ __launch_bounds__(256) void cvt_wo_kernel(
    const float* __restrict__ Wo, unsigned short* __restrict__ Wob)
{
    int idx = blockIdx.x * 256 + threadIdx.x;     // float4 index, 262144 total
    float4 w = ((const float4*)Wo)[idx];
    uint2 p; p.x = packbf2(w.x, w.y); p.y = packbf2(w.z, w.w);
    ((uint2*)Wob)[idx] = p;
}

// ---------------------------------------------------------------------------
// Kernel 1: per-head QKV projection (bf16 MFMA).  grid (SEQ/64, NH, 3*NB).
// Q,K out: [n][h][l][d] bf16 (Q pre-scaled by 1/32).  V out: [n][h][d][l].
// ---------------------------------------------------------------------------
__global__ __launch_bounds__(256) void qkv_kernel(
    const float* __restrict__ Qin, const float* __restrict__ Kin,
    const float* __restrict__ Vin,
    const float* __restrict__ Wq, const float* __restrict__ Wk,
    const float* __restrict__ Wv, const float* __restrict__ bq,
    unsigned short* __restrict__ Qp, unsigned short* __restrict__ Kp,
    unsigned short* __restrict__ Vtp)
{
    const int lt = blockIdx.x;
    const int h  = blockIdx.y;
    const int tz = blockIdx.z;
    const int t  = tz >> 1;             // 0=q, 1=k, 2=v
    const int n  = tz & 1;

    const float* X; const float* W;
    if (t == 0)      { X = Qin; W = Wq; }
    else if (t == 1) { X = Kin; W = Wk; }
    else             { X = Vin; W = Wv; }

    __shared__ __align__(16) unsigned short sX[64][72];
    __shared__ __align__(16) unsigned short sW[64][72];
    __shared__ __align__(16) unsigned short sT[64][72];

    const int tid  = threadIdx.x;
    const int wave = tid >> 6, lane = tid & 63;
    const int ln   = lane & 15, quad = lane >> 4;

    #pragma unroll
    for (int i = 0; i < 4; ++i) {
        int flat = tid + i * 256;
        int r = flat >> 4, c4 = flat & 15;
        float4 xv = *(const float4*)(X + ((size_t)(n * SEQ + lt * 64 + r)) * EMB + h * HD + c4 * 4);
        uint2 xp; xp.x = packbf2(xv.x, xv.y); xp.y = packbf2(xv.z, xv.w);
        *(uint2*)&sX[r][c4 * 4] = xp;
        float4 wv = *(const float4*)(W + r * HD + c4 * 4);
        uint2 wp; wp.x = packbf2(wv.x, wv.y); wp.y = packbf2(wv.z, wv.w);
        *(uint2*)&sW[r][c4 * 4] = wp;
    }
    __syncthreads();

    short8 af0 = *(const short8*)&sX[wave * 16 + ln][quad * 8];
    short8 af1 = *(const short8*)&sX[wave * 16 + ln][32 + quad * 8];

    f32x4 acc[4];
    #pragma unroll
    for (int nt = 0; nt < 4; ++nt) {
        short8 bf0 = *(const short8*)&sW[nt * 16 + ln][quad * 8];
        short8 bf1 = *(const short8*)&sW[nt * 16 + ln][32 + quad * 8];
        f32x4 a = {0.f, 0.f, 0.f, 0.f};
        a = MFMA(af0, bf0, a);
        a = MFMA(af1, bf1, a);
        acc[nt] = a;
    }

    if (t == 0) {   // bias then exact pow2 scale
        #pragma unroll
        for (int nt = 0; nt < 4; ++nt) {
            float bb = bq[nt * 16 + ln];
            #pragma unroll
            for (int a = 0; a < 4; ++a) acc[nt][a] = (acc[nt][a] + bb) * SCALE;
        }
    }

    if (t < 2) {
        unsigned short* Out = (t == 0) ? Qp : Kp;
        #pragma unroll
        for (int a = 0; a < 4; ++a) {
            size_t row = (size_t)((n * NH + h) * SEQ + lt * 64 + wave * 16 + quad * 4 + a);
            #pragma unroll
            for (int nt = 0; nt < 4; ++nt)
                Out[row * HD + nt * 16 + ln] = f2bf(acc[nt][a]);
        }
    } else {
        #pragma unroll
        for (int nt = 0; nt < 4; ++nt)
            #pragma unroll
            for (int a = 0; a < 4; ++a)
                sT[nt * 16 + ln][wave * 16 + quad * 4 + a] = f2bf(acc[nt][a]);
        __syncthreads();
        #pragma unroll
        for (int i = 0; i < 2; ++i) {
            int flat = tid + i * 256;
            int r = flat >> 3, c8 = flat & 7;
            *(float4*)(Vtp + ((size_t)((n * NH + h) * HD + r)) * SEQ + lt * 64 + c8 * 8) =
                *(const float4*)&sT[r][c8 * 8];
        }
    }
}

// ---------------------------------------------------------------------------
// Kernel 2: flash attention, S^T trick + sum-softmax (no online max).
// grid (NB*NH, SEQ/64)  [nh fastest -> XCD L2 locality], block 128 (2 waves).
// Each wave owns 32 q-rows (2 MFMA row-sets), K/V frags reused across sets.
// ---------------------------------------------------------------------------
__global__ __launch_bounds__(128, 2) void flash_kernel(
    const unsigned short* __restrict__ Qp, const unsigned short* __restrict__ Kp,
    const unsigned short* __restrict__ Vtp, const int* __restrict__ mask,
    unsigned short* __restrict__ A /* [n][l][EMB] bf16 */)
{
    const int nh = blockIdx.x;
    const int qt = blockIdx.y;
    const int n  = nh >> 4, h = nh & 15;

    const int tid  = threadIdx.x;
    const int wave = tid >> 6, lane = tid & 63;
    const int ln   = lane & 15, quad = lane >> 4;

    __shared__ __align__(16) unsigned short sK [64][72];  // [key][d]
    __shared__ __align__(16) unsigned short sVt[64][72];  // [d][key]
    __shared__ __align__(16) unsigned short sP [64][72];  // [q(64)][key]
    __shared__ float sMadd[SEQ];                          // 0 or -1e20*SCALE

    for (int i = tid; i < SEQ; i += 128)
        sMadd[i] = mask[n * SEQ + i] ? 0.f : MADD;

    // Q B-fragments: q-row = qt*64 + wave*32 + set*16 + ln (Q pre-scaled)
    const unsigned short* Qb = Qp + ((size_t)nh * SEQ + qt * 64 + wave * 32) * HD;
    short8 qf0[2], qf1[2];
    #pragma unroll
    for (int set = 0; set < 2; ++set) {
        qf0[set] = *(const short8*)(Qb + (set * 16 + ln) * HD + quad * 8);
        qf1[set] = *(const short8*)(Qb + (set * 16 + ln) * HD + 32 + quad * 8);
    }

    const unsigned short* Kb = Kp  + (size_t)nh * SEQ * HD;
    const unsigned short* Vb = Vtp + (size_t)nh * HD * SEQ;

    f32x4 o[2][4];
    #pragma unroll
    for (int s2 = 0; s2 < 2; ++s2)
        #pragma unroll
        for (int dt = 0; dt < 4; ++dt) o[s2][dt] = (f32x4){0.f, 0.f, 0.f, 0.f};
    float lsum[2] = {0.f, 0.f};

    for (int kt = 0; kt < SEQ / 64; ++kt) {
        __syncthreads();   // prev readers done (also covers sMadd on kt=0)
        #pragma unroll
        for (int i = 0; i < 4; ++i) {
            int flat = tid + i * 128; int r = flat >> 3, c8 = flat & 7;
            *(float4*)&sK [r][c8 * 8] = *(const float4*)(Kb + ((size_t)(kt * 64 + r)) * HD + c8 * 8);
            *(float4*)&sVt[r][c8 * 8] = *(const float4*)(Vb + (size_t)r * SEQ + kt * 64 + c8 * 8);
        }
        __syncthreads();

        // ---- S^T = K Q^T : row=key (quad*4+a), col=q (ln) ----
        f32x4 s[2][4];
        #pragma unroll
        for (int nt = 0; nt < 4; ++nt) {
            short8 kf0 = *(const short8*)&sK[nt * 16 + ln][quad * 8];
            short8 kf1 = *(const short8*)&sK[nt * 16 + ln][32 + quad * 8];
            f32x4 z0 = {0.f, 0.f, 0.f, 0.f};
            f32x4 z1 = {0.f, 0.f, 0.f, 0.f};
            z0 = MFMA(kf0, qf0[0], z0);
            z0 = MFMA(kf1, qf1[0], z0);
            z1 = MFMA(kf0, qf0[1], z1);
            z1 = MFMA(kf1, qf1[1], z1);
            s[0][nt] = z0; s[1][nt] = z1;
        }

        // ---- sum-softmax: p = exp(s + madd), accumulate l; P -> LDS ----
        #pragma unroll
        for (int set = 0; set < 2; ++set) {
            #pragma unroll
            for (int nt = 0; nt < 4; ++nt) {
                float4 md = *(const float4*)&sMadd[kt * 64 + nt * 16 + quad * 4];
                float p0 = __expf(fminf(s[set][nt][0] + md.x, 60.f));
                float p1 = __expf(fminf(s[set][nt][1] + md.y, 60.f));
                float p2 = __expf(fminf(s[set][nt][2] + md.z, 60.f));
                float p3 = __expf(fminf(s[set][nt][3] + md.w, 60.f));
                lsum[set] += (p0 + p1) + (p2 + p3);
                uint2 w; w.x = packbf2(p0, p1); w.y = packbf2(p2, p3);
                *(uint2*)&sP[wave * 32 + set * 16 + ln][nt * 16 + quad * 4] = w;
            }
        }
        // per-wave sP region: drain LDS, no block barrier needed
        asm volatile("s_waitcnt lgkmcnt(0)" ::: "memory");

        // ---- O += P V (V frags reused across both q-sets) ----
        short8 vf0[4], vf1[4];
        #pragma unroll
        for (int dt = 0; dt < 4; ++dt) {
            vf0[dt] = *(const short8*)&sVt[dt * 16 + ln][quad * 8];
            vf1[dt] = *(const short8*)&sVt[dt * 16 + ln][32 + quad * 8];
        }
        #pragma unroll
        for (int set = 0; set < 2; ++set) {
            short8 pf0 = *(const short8*)&sP[wave * 32 + set * 16 + ln][quad * 8];
            short8 pf1 = *(const short8*)&sP[wave * 32 + set * 16 + ln][32 + quad * 8];
            #pragma unroll
            for (int dt = 0; dt < 4; ++dt) {
                o[set][dt] = MFMA(pf0, vf0[dt], o[set][dt]);
                o[set][dt] = MFMA(pf1, vf1[dt], o[set][dt]);
            }
        }
    }

    // ---- epilogue: reduce l over quads, normalize, store bf16 ----
    #pragma unroll
    for (int set = 0; set < 2; ++set) {
        float l = lsum[set];
        l += __shfl_xor(l, 16);
        l += __shfl_xor(l, 32);          // every lane: full l for q-row set*16+ln
        #pragma unroll
        for (int a = 0; a < 4; ++a) {
            float lr  = __shfl(l, (lane & 48) | (quad * 4 + a));
            float inv = 1.0f / lr;
            size_t row = (size_t)(n * SEQ + qt * 64 + wave * 32 + set * 16 + quad * 4 + a);
            #pragma unroll
            for (int dt = 0; dt < 4; ++dt)
                A[row * EMB + h * HD + dt * 16 + ln] = f2bf(o[set][dt][a] * inv);
        }
    }
}

// ---------------------------------------------------------------------------
// Kernel 3: out = A @ Wo^T + bo (bf16 MFMA, bf16 pre-converted Wo, fp32 out).
// grid (EMB/64, NB*SEQ/64), block 256.
// ---------------------------------------------------------------------------
__global__ __launch_bounds__(256) void outproj_kernel(
    const unsigned short* __restrict__ A, const unsigned short* __restrict__ Wob,
    const float* __restrict__ bo, float* __restrict__ Out)
{
    const int ct = blockIdx.x;
    const int rt = blockIdx.y;

    const int tid  = threadIdx.x;
    const int wave = tid >> 6, lane = tid & 63;
    const int ln   = lane & 15, quad = lane >> 4;

    __shared__ __align__(16) unsigned short sA[64][72];
    __shared__ __align__(16) unsigned short sW[64][72];

    f32x4 acc[4];
    #pragma unroll
    for (int nt = 0; nt < 4; ++nt) acc[nt] = (f32x4){0.f, 0.f, 0.f, 0.f};

    for (int kc = 0; kc < EMB / 64; ++kc) {
        __syncthreads();
        #pragma unroll
        for (int i = 0; i < 2; ++i) {
            int flat = tid + i * 256; int r = flat >> 3, c8 = flat & 7;
            *(float4*)&sA[r][c8 * 8] =
                *(const float4*)(A + (size_t)(rt * 64 + r) * EMB + kc * 64 + c8 * 8);
            *(float4*)&sW[r][c8 * 8] =
                *(const float4*)(Wob + (size_t)(ct * 64 + r) * EMB + kc * 64 + c8 * 8);
        }
        __syncthreads();

        short8 af0 = *(const short8*)&sA[wave * 16 + ln][quad * 8];
        short8 af1 = *(const short8*)&sA[wave * 16 + ln][32 + quad * 8];
        #pragma unroll
        for (int nt = 0; nt < 4; ++nt) {
            short8 bf0 = *(const short8*)&sW[nt * 16 + ln][quad * 8];
            short8 bf1 = *(const short8*)&sW[nt * 16 + ln][32 + quad * 8];
            acc[nt] = MFMA(af0, bf0, acc[nt]);
            acc[nt] = MFMA(af1, bf1, acc[nt]);
        }
    }

    #pragma unroll
    for (int nt = 0; nt < 4; ++nt) {
        float bb = bo[ct * 64 + nt * 16 + ln];
        #pragma unroll
        for (int a = 0; a < 4; ++a) {
            size_t row = (size_t)(rt * 64 + wave * 16 + quad * 4 + a);
            Out[row * EMB + ct * 64 + nt * 16 + ln] = acc[nt][a] + bb;
        }
    }
}

// ---------------------------------------------------------------------------
extern "C" void kernel_launch(void* const* d_in, const int* in_sizes, int n_in,
                              void* d_out, int out_size, void* d_ws, size_t ws_size,
                              hipStream_t stream) {
    const float* values = (const float*)d_in[0];
    const float* key_   = (const float*)d_in[1];
    const float* query  = (const float*)d_in[2];
    const int*   mask   = (const int*)d_in[3];
    const float* Wv     = (const float*)d_in[4];
    const float* Wk     = (const float*)d_in[5];
    const float* Wq     = (const float*)d_in[6];
    const float* bq     = (const float*)d_in[7];
    const float* Wo     = (const float*)d_in[8];
    const float* bo     = (const float*)d_in[9];
    float* out = (float*)d_out;

    unsigned short* ws = (unsigned short*)d_ws;
    const size_t NHLD = (size_t)NB * NH * SEQ * HD;   // 4,194,304 elements
    unsigned short* Qp    = ws;
    unsigned short* Kp    = ws + NHLD;
    unsigned short* Vtp   = ws + 2 * NHLD;
    unsigned short* Aattn = ws + 3 * NHLD;            // [n][l][EMB] bf16
    unsigned short* Wob   = ws + 4 * NHLD;            // [EMB][EMB] bf16

    cvt_wo_kernel<<<dim3(1024), 256, 0, stream>>>(Wo, Wob);
    qkv_kernel<<<dim3(SEQ / 64, NH, 3 * NB), 256, 0, stream>>>(
        query, key_, values, Wq, Wk, Wv, bq, Qp, Kp, Vtp);
    flash_kernel<<<dim3(NB * NH, SEQ / 64), 128, 0, stream>>>(
        Qp, Kp, Vtp, mask, Aattn);
    outproj_kernel<<<dim3(EMB / 64, NB * SEQ / 64), 256, 0, stream>>>(
        Aattn, Wob, bo, out);
}